// Round 11
// baseline (104.943 us; speedup 1.0000x reference)
//
#include <hip/hip_runtime.h>
#include <hip/hip_bf16.h>

#define MDIM 16384
#define NDIM 1024
#define KDIM 512
#define BM 128
#define BN 128
#define BK 64
#define KT (KDIM / BK)   // 8

typedef __attribute__((ext_vector_type(8))) short bf16x8;
typedef __attribute__((ext_vector_type(4))) short bf16x4;
typedef __attribute__((ext_vector_type(4))) float f32x4;

__device__ __forceinline__ short f2bf(float f) {
    union { float f; unsigned u; } v; v.f = f;
    unsigned r = v.u + 0x7fff + ((v.u >> 16) & 1);   // RNE truncate to bf16
    return (short)(r >> 16);
}

__device__ __forceinline__ bf16x8 cvt8(float4 a, float4 b) {
    bf16x8 o;
    o[0] = f2bf(a.x); o[1] = f2bf(a.y); o[2] = f2bf(a.z); o[3] = f2bf(a.w);
    o[4] = f2bf(b.x); o[5] = f2bf(b.y); o[6] = f2bf(b.z); o[7] = f2bf(b.w);
    return o;
}

__device__ __forceinline__ void gload_lds16(const void* g, void* l) {
    __builtin_amdgcn_global_load_lds(
        (const __attribute__((address_space(1))) void*)g,
        (__attribute__((address_space(3))) void*)l, 16, 0, 0);
}

// ---------- tiny pre-pass (R8/R9-verified): P fp32 -> bf16 + exact psq ----------
__global__ __launch_bounds__(256) void convert_p(
        const float* __restrict__ P, short* __restrict__ Pbf,
        float* __restrict__ psq) {
    int wave = (blockIdx.x * blockDim.x + threadIdx.x) >> 6;   // 0..1023
    int lane = threadIdx.x & 63;
    const float4* r4 = (const float4*)(P + (size_t)wave * KDIM) + lane * 2;
    float4 a = r4[0], b = r4[1];
    *(bf16x8*)(Pbf + (size_t)wave * KDIM + lane * 8) = cvt8(a, b);
    float s = a.x*a.x + a.y*a.y + a.z*a.z + a.w*a.w
            + b.x*b.x + b.y*b.y + b.z*b.z + b.w*b.w;
    #pragma unroll
    for (int off = 32; off; off >>= 1) s += __shfl_down(s, off, 64);
    if (lane == 0) psq[wave] = s;
}

// ---------- fused main kernel: A-convert + xsq + GEMM + epilogue ----------
// 512 thr, 8 waves (2M x 4N, 64x32/wave, acc[4][2]=32 VGPR). A staged from
// fp32 X in registers (ra[4]=16 VGPR held across compute -- the lean redo of
// R7 whose 256-thr geometry spilled), converted to bf16 LDS with the verified
// symmetric XOR swizzle; exact fp32 xsq accumulated during staging (each X
// element passes through regs exactly once; 8-way col-block redundancy is
// VALU-cheap). B staged from Pbf via gload_lds w16 (linear dest + pre-XOR
// source, rule #21; verbatim R6-verified). 64.5 KB LDS -> 2 blocks/CU.
__global__ __launch_bounds__(512, 4) void dist_fused2(
        const float* __restrict__ X, const short* __restrict__ Pbf,
        const float* __restrict__ psq, float* __restrict__ out) {
    __shared__ short As[2][BM * BK];   // 2 x 16 KB
    __shared__ short Bs[2][BN * BK];   // 2 x 16 KB
    __shared__ float xs_l[BM];

    int tid = threadIdx.x;
    int bid = blockIdx.x;
    // XCD-aware mapping (perf heuristic only): bid&7 -> XCD; the 8 colb of one
    // rowb are consecutive j -> co-resident on one XCD; X panel read 8x from L2.
    int x = bid & 7, j = bid >> 3;           // j in 0..127
    int colb = j & 7, rowb = x * 16 + (j >> 3);
    int row0 = rowb * BM, col0 = colb * BN;

    int lane = tid & 63, wid = tid >> 6;
    int wr = wid >> 2, wc = wid & 3;         // 2(M) x 4(N); wave = 64 x 32

    f32x4 acc[4][2] = {};

    // ---- A reg-staging geometry: thread owns row = tid>>2, quad q = tid&3;
    //      per tile loads 4 float4 at slots {i*4+q}  (4 thr x 4 = 16 slots) ----
    int arow = tid >> 2, q = tid & 3;
    const float4* rp4 = (const float4*)(X + (size_t)(row0 + arow) * KDIM);
    float4 ra[4];
    float ssq = 0.f;

    auto loadA = [&](int kt) {
        #pragma unroll
        for (int i = 0; i < 4; ++i)
            ra[i] = rp4[kt * 16 + i * 4 + q];
    };
    auto commitA = [&](int sel) {
        #pragma unroll
        for (int i = 0; i < 4; ++i) {
            float4 a = ra[i];
            ssq += a.x * a.x + a.y * a.y + a.z * a.z + a.w * a.w;
            bf16x4 av;
            av[0] = f2bf(a.x); av[1] = f2bf(a.y); av[2] = f2bf(a.z); av[3] = f2bf(a.w);
            int col4 = i * 4 + q;
            int off = (arow * (BK * 2) + col4 * 8) ^ ((arow & 7) << 4);
            *(bf16x4*)((char*)&As[sel][0] + off) = av;
        }
    };
    // ---- B staging via gload_lds (verbatim R6-verified form) ----
    const short* Bb = Pbf + (size_t)col0 * KDIM;
    auto stageB = [&](int sel, int kt) {
        #pragma unroll
        for (int s = 0; s < 2; ++s) {
            int c = s * 512 + tid;               // chunk 0..1023
            int row = c >> 3;                    // 0..127
            int g16 = (c & 7) ^ (row & 7);       // pre-swizzled source slot
            const char* gb = (const char*)(Bb + (size_t)row * KDIM)
                             + (size_t)kt * (BK * 2) + g16 * 16;
            gload_lds16(gb, (char*)&Bs[sel][0] + s * 8192 + wid * 1024);
        }
    };

    auto lds_off = [&](int row, int kb) {
        return (row * (BK * 2) + kb) ^ ((row & 7) << 4);
    };
    auto compute = [&](int sel) {
        const char* aB = (const char*)&As[sel][0];
        const char* bB = (const char*)&Bs[sel][0];
        #pragma unroll
        for (int ks = 0; ks < 2; ++ks) {
            int kb = ks * 64 + ((lane >> 4) * 16);
            bf16x8 af[4], bfr[2];
            #pragma unroll
            for (int m = 0; m < 4; ++m)
                af[m] = *(const bf16x8*)(aB +
                    lds_off(wr * 64 + m * 16 + (lane & 15), kb));
            #pragma unroll
            for (int n = 0; n < 2; ++n)
                bfr[n] = *(const bf16x8*)(bB +
                    lds_off(wc * 32 + n * 16 + (lane & 15), kb));
            #pragma unroll
            for (int m = 0; m < 4; ++m)
                #pragma unroll
                for (int n = 0; n < 2; ++n)
                    acc[m][n] = __builtin_amdgcn_mfma_f32_16x16x32_bf16(
                        af[m], bfr[n], acc[m][n], 0, 0, 0);
        }
    };

    // prologue: tile 0
    stageB(0, 0);
    loadA(0);
    commitA(0);
    __syncthreads();           // drains gload B(0) + ds_write A(0)

    #pragma unroll
    for (int t = 0; t < KT - 1; ++t) {
        int cur = t & 1;
        stageB(cur ^ 1, t + 1);  // in flight across compute
        loadA(t + 1);            // ra[4] in flight across compute
        compute(cur);
        commitA(cur ^ 1);        // cvt + swizzled ds_write + ssq accumulate
        __syncthreads();         // all staging resident; roles flip
    }
    compute((KT - 1) & 1);       // tile 7

    // finish xsq: 4 threads per row (adjacent lanes) -> xs_l
    ssq += __shfl_xor(ssq, 1, 64);
    ssq += __shfl_xor(ssq, 2, 64);
    if (q == 0) xs_l[arow] = ssq;
    __syncthreads();

    // epilogue: C/D layout col = lane&15, row = (lane>>4)*4 + reg  [m89]
    int cr = (lane >> 4) * 4;
    int cc = lane & 15;
    float ps[2];
    #pragma unroll
    for (int n = 0; n < 2; ++n) ps[n] = psq[col0 + wc * 32 + n * 16 + cc];
    #pragma unroll
    for (int m = 0; m < 4; ++m) {
        #pragma unroll
        for (int r = 0; r < 4; ++r) {
            int lr = wr * 64 + m * 16 + cr + r;
            float xv = xs_l[lr];
            size_t ob = (size_t)(row0 + lr) * NDIM + col0;
            #pragma unroll
            for (int n = 0; n < 2; ++n)
                out[ob + wc * 32 + n * 16 + cc] = 2.0f * acc[m][n][r] - xv - ps[n];
        }
    }
}

// ---------- fallback path (R1-verified fp32 kernels, used if ws too small) ----------
__global__ __launch_bounds__(256) void sumsq_kernel(
        const float* __restrict__ X, const float* __restrict__ P,
        float* __restrict__ xsq, float* __restrict__ psq) {
    int wave = (blockIdx.x * blockDim.x + threadIdx.x) >> 6;
    int lane = threadIdx.x & 63;
    const float* src; float* dst; int row;
    if (wave < MDIM) { src = X; dst = xsq; row = wave; }
    else             { src = P; dst = psq; row = wave - MDIM; }
    const float4* r4 = (const float4*)(src + (size_t)row * KDIM) + lane * 2;
    float4 a = r4[0], b = r4[1];
    float s = a.x*a.x + a.y*a.y + a.z*a.z + a.w*a.w
            + b.x*b.x + b.y*b.y + b.z*b.z + b.w*b.w;
    #pragma unroll
    for (int off = 32; off; off >>= 1) s += __shfl_down(s, off, 64);
    if (lane == 0) dst[row] = s;
}

__global__ __launch_bounds__(256) void dist_gemm(
        const float* __restrict__ X, const float* __restrict__ P,
        const float* __restrict__ xsq, const float* __restrict__ psq,
        float* __restrict__ out) {
    __shared__ short As[128 * BK];
    __shared__ short Bs[128 * BK];
    int tid = threadIdx.x;
    int bid = blockIdx.x;
    int swz = (bid & 7) * 128 + (bid >> 3);
    int bn = swz & 7, bm = swz >> 3;
    int row0 = bm * 128, col0 = bn * 128;
    int lane = tid & 63, wid = tid >> 6;
    int wm = (wid >> 1) * 64, wn = (wid & 1) * 64;
    f32x4 acc[4][4] = {};
    int rbase = tid >> 3;
    int kg = tid & 7;
    const float* Abase = X + (size_t)row0 * KDIM;
    const float* Bbase = P + (size_t)col0 * KDIM;
    for (int kt = 0; kt < KDIM / BK; ++kt) {
        int kofs = kt * BK + kg * 8;
        __syncthreads();
        #pragma unroll
        for (int i = 0; i < 4; ++i) {
            int row = rbase + 32 * i;
            const float4* ga = (const float4*)(Abase + (size_t)row * KDIM + kofs);
            float4 a0 = ga[0], a1 = ga[1];
            const float4* gb = (const float4*)(Bbase + (size_t)row * KDIM + kofs);
            float4 b0 = gb[0], b1 = gb[1];
            int off = (row * (BK * 2) + kg * 16) ^ ((row & 7) << 4);
            *(bf16x8*)((char*)As + off) = cvt8(a0, a1);
            *(bf16x8*)((char*)Bs + off) = cvt8(b0, b1);
        }
        __syncthreads();
        #pragma unroll
        for (int ks = 0; ks < 2; ++ks) {
            bf16x8 af[4], bfr[4];
            int kb = ks * 64 + ((lane >> 4) * 16);
            #pragma unroll
            for (int m = 0; m < 4; ++m) {
                int row = wm + m * 16 + (lane & 15);
                int off = (row * (BK * 2) + kb) ^ ((row & 7) << 4);
                af[m] = *(const bf16x8*)((const char*)As + off);
            }
            #pragma unroll
            for (int n = 0; n < 4; ++n) {
                int row = wn + n * 16 + (lane & 15);
                int off = (row * (BK * 2) + kb) ^ ((row & 7) << 4);
                bfr[n] = *(const bf16x8*)((const char*)Bs + off);
            }
            #pragma unroll
            for (int m = 0; m < 4; ++m)
                #pragma unroll
                for (int n = 0; n < 4; ++n)
                    acc[m][n] = __builtin_amdgcn_mfma_f32_16x16x32_bf16(
                        af[m], bfr[n], acc[m][n], 0, 0, 0);
        }
    }
    int cr = (lane >> 4) * 4;
    int cc = lane & 15;
    #pragma unroll
    for (int n = 0; n < 4; ++n) {
        int gc = col0 + wn + n * 16 + cc;
        float ps = psq[gc];
        #pragma unroll
        for (int m = 0; m < 4; ++m) {
            int grb = row0 + wm + m * 16 + cr;
            #pragma unroll
            for (int r = 0; r < 4; ++r) {
                float v = 2.0f * acc[m][n][r] - xsq[grb + r] - ps;
                out[(size_t)(grb + r) * NDIM + gc] = v;
            }
        }
    }
}

extern "C" void kernel_launch(void* const* d_in, const int* in_sizes, int n_in,
                              void* d_out, int out_size, void* d_ws, size_t ws_size,
                              hipStream_t stream) {
    const float* X = (const float*)d_in[0];
    const float* P = (const float*)d_in[1];
    float* out = (float*)d_out;

    const size_t need = (size_t)NDIM * KDIM * 2 + (size_t)NDIM * 4;  // Pbf + psq

    if (ws_size >= need) {
        short* Pbf = (short*)d_ws;                        // 1 MB
        float* psq = (float*)(Pbf + (size_t)NDIM * KDIM); // 4 KB
        convert_p<<<NDIM / 4, 256, 0, stream>>>(P, Pbf, psq);
        dist_fused2<<<(MDIM / BM) * (NDIM / BN), 512, 0, stream>>>(X, Pbf, psq, out);
    } else {
        float* xsq = (float*)d_ws;
        float* psq = xsq + MDIM;
        sumsq_kernel<<<(MDIM + NDIM) / 4, 256, 0, stream>>>(X, P, xsq, psq);
        dist_gemm<<<(MDIM / 128) * (NDIM / 128), 256, 0, stream>>>(X, P, xsq, psq, out);
    }
}